// Round 1
// baseline (1041.358 us; speedup 1.0000x reference)
//
#include <hip/hip_runtime.h>
#include <hip/hip_bf16.h>
#include <stdint.h>

#define M_DIM 8192
#define K_DIM 4096
#define N_DIM 12288

#define BM 128
#define BN 128
#define BK 64

typedef int v4i __attribute__((ext_vector_type(4)));

// ---------------------------------------------------------------------------
// Pack x: int32 [M][K] -> int8 [M][K]
// ---------------------------------------------------------------------------
__global__ __launch_bounds__(256) void pack_x_kernel(const int* __restrict__ xi,
                                                     uint32_t* __restrict__ xq,
                                                     int n4) {
    int i = blockIdx.x * blockDim.x + threadIdx.x;
    const int stride = gridDim.x * blockDim.x;
    for (; i < n4; i += stride) {
        v4i v = ((const v4i*)xi)[i];
        uint32_t p = (uint32_t)(v[0] & 0xff)
                   | ((uint32_t)(v[1] & 0xff) << 8)
                   | ((uint32_t)(v[2] & 0xff) << 16)
                   | ((uint32_t)(v[3] & 0xff) << 24);
        xq[i] = p;
    }
}

// ---------------------------------------------------------------------------
// Pack + transpose w: int32 [K][N] -> int8 wT [N][K]
// 64x64 tile through LDS; coalesced dword reads and writes.
// ---------------------------------------------------------------------------
__global__ __launch_bounds__(256) void packt_w_kernel(const int* __restrict__ wi,
                                                      uint8_t* __restrict__ wt) {
    __shared__ uint8_t t[64][68];   // +4 pad breaks bank conflicts
    const int n0 = blockIdx.x * 64;
    const int k0 = blockIdx.y * 64;
    const int tid = threadIdx.x;

#pragma unroll
    for (int i = 0; i < 4; ++i) {
        int d = tid + i * 256;          // 0..1023 dword-groups
        int k = d >> 4;                 // 0..63 (k row)
        int ng = d & 15;                // dword group along n
        v4i v = *(const v4i*)(wi + (size_t)(k0 + k) * N_DIM + n0 + ng * 4);
        t[ng * 4 + 0][k] = (uint8_t)(v[0] & 0xff);
        t[ng * 4 + 1][k] = (uint8_t)(v[1] & 0xff);
        t[ng * 4 + 2][k] = (uint8_t)(v[2] & 0xff);
        t[ng * 4 + 3][k] = (uint8_t)(v[3] & 0xff);
    }
    __syncthreads();
#pragma unroll
    for (int i = 0; i < 4; ++i) {
        int d = tid + i * 256;
        int n = d >> 4;                 // 0..63 (n row of wT tile)
        int kd = d & 15;                // dword along k
        uint32_t v = *(const uint32_t*)(&t[n][kd * 4]);
        *(uint32_t*)(wt + (size_t)(n0 + n) * K_DIM + k0 + kd * 4) = v;
    }
}

// ---------------------------------------------------------------------------
// Main GEMM: xq [M][K] i8  x  wT [N][K] i8  ->  out [M][N] f32 (dequant)
// m97 structure: 128x128 tile, BK=64, 4 waves 2x2, mfma_i32_16x16x64_i8.
// ---------------------------------------------------------------------------
__global__ __launch_bounds__(256) void gemm_i8_kernel(const int8_t* __restrict__ xq,
                                                      const int8_t* __restrict__ wt,
                                                      const float* __restrict__ clampv,
                                                      float* __restrict__ out) {
    __shared__ int8_t As[BM * BK];   // 8 KB, [BM][BK] row-major
    __shared__ int8_t Bs[BN * BK];   // 8 KB, [BN][BK] row-major (wT layout)

    const int tid  = threadIdx.x;
    const int lane = tid & 63;
    const int wid  = tid >> 6;
    const int wr   = wid >> 1;       // wave row 0..1 (owns 64 rows)
    const int wc   = wid & 1;        // wave col 0..1 (owns 64 cols)

    const size_t row0 = (size_t)blockIdx.y * BM;
    const size_t col0 = (size_t)blockIdx.x * BN;
    const int8_t* Ag = xq + row0 * K_DIM;
    const int8_t* Bg = wt + col0 * K_DIM;

    v4i acc[4][4];
#pragma unroll
    for (int m = 0; m < 4; ++m)
#pragma unroll
        for (int n = 0; n < 4; ++n) acc[m][n] = (v4i){0, 0, 0, 0};

    // staging: 8192 B per tile; 256 threads x 16 B = 4096 B per issue -> 2 issues
    const int off0 = tid * 16;
    const int off1 = off0 + 4096;
    const int r0 = off0 >> 6, c0 = off0 & 63;
    const int r1 = off1 >> 6, c1 = off1 & 63;

    const int fr = lane & 15;            // fragment row (A) / col (B)
    const int fk = (lane >> 4) * 16;     // k byte offset within BK

    for (int kt = 0; kt < K_DIM / BK; ++kt) {
        const int kb = kt * BK;
        __builtin_amdgcn_global_load_lds(
            (const __attribute__((address_space(1))) uint32_t*)(Ag + (size_t)r0 * K_DIM + kb + c0),
            (__attribute__((address_space(3))) uint32_t*)(As + off0), 16, 0, 0);
        __builtin_amdgcn_global_load_lds(
            (const __attribute__((address_space(1))) uint32_t*)(Ag + (size_t)r1 * K_DIM + kb + c1),
            (__attribute__((address_space(3))) uint32_t*)(As + off1), 16, 0, 0);
        __builtin_amdgcn_global_load_lds(
            (const __attribute__((address_space(1))) uint32_t*)(Bg + (size_t)r0 * K_DIM + kb + c0),
            (__attribute__((address_space(3))) uint32_t*)(Bs + off0), 16, 0, 0);
        __builtin_amdgcn_global_load_lds(
            (const __attribute__((address_space(1))) uint32_t*)(Bg + (size_t)r1 * K_DIM + kb + c1),
            (__attribute__((address_space(3))) uint32_t*)(Bs + off1), 16, 0, 0);
        __syncthreads();   // emits vmcnt(0) drain + barrier

        v4i af[4], bf[4];
#pragma unroll
        for (int m = 0; m < 4; ++m)
            af[m] = *(const v4i*)(As + (wr * 64 + m * 16 + fr) * BK + fk);
#pragma unroll
        for (int n = 0; n < 4; ++n)
            bf[n] = *(const v4i*)(Bs + (wc * 64 + n * 16 + fr) * BK + fk);

#pragma unroll
        for (int m = 0; m < 4; ++m)
#pragma unroll
            for (int n = 0; n < 4; ++n)
                acc[m][n] = __builtin_amdgcn_mfma_i32_16x16x64_i8(af[m], bf[n], acc[m][n], 0, 0, 0);
        __syncthreads();
    }

    // epilogue: C/D layout col = lane&15, row = (lane>>4)*4 + reg
    const int crow_base = (int)row0 + wr * 64 + (lane >> 4) * 4;
    const int ccol_base = (int)col0 + wc * 64 + fr;
#pragma unroll
    for (int m = 0; m < 4; ++m) {
#pragma unroll
        for (int j = 0; j < 4; ++j) {
            const int row = crow_base + m * 16 + j;
            const float s = clampv[row] * (1.0f / 127.0f);
#pragma unroll
            for (int n = 0; n < 4; ++n) {
                const int col = ccol_base + n * 16;
                out[(size_t)row * N_DIM + col] = (float)acc[m][n][j] * s;
            }
        }
    }
}

// ---------------------------------------------------------------------------
extern "C" void kernel_launch(void* const* d_in, const int* in_sizes, int n_in,
                              void* d_out, int out_size, void* d_ws, size_t ws_size,
                              hipStream_t stream) {
    const int*   wi     = (const int*)d_in[0];    // w_int_repr_t [K][N] int32
    const float* clampv = (const float*)d_in[1];  // [M] f32
    const int*   xi     = (const int*)d_in[2];    // x [M][K] int32
    float*       out    = (float*)d_out;

    uint8_t* xq = (uint8_t*)d_ws;                               // 32 MB
    uint8_t* wt = (uint8_t*)d_ws + (size_t)M_DIM * K_DIM;       // 48 MB

    pack_x_kernel<<<2048, 256, 0, stream>>>(xi, (uint32_t*)xq, M_DIM * K_DIM / 4);
    packt_w_kernel<<<dim3(N_DIM / 64, K_DIM / 64), 256, 0, stream>>>(wi, wt);
    gemm_i8_kernel<<<dim3(N_DIM / BN, M_DIM / BM), 256, 0, stream>>>(
        (const int8_t*)xq, (const int8_t*)wt, clampv, out);
}